// Round 1
// baseline (156.213 us; speedup 1.0000x reference)
//
#include <hip/hip_runtime.h>

// Problem: unbiased EWMA mean/var normalization over T, s:(16,2000,257,2) fp32.
// Layout: idx = ((n*T + t)*F + f)*C + c  ->  series stride over t is F*C = 514.
//
// Strategy:
//  - One thread per (n,f,c) series slice; sequential over t (clamp S>0 breaks
//    scan associativity, so no exact parallel scan).
//  - Chunk T into NCHUNK=7 chunks of CLEN=286 with WARM=512 warm-up steps
//    (state error decays by beta^512 ~ 5.9e-3; well under the 0.1 threshold).
//    7 chunks * 129 wave-blocks = 903 waves <= 1024 SIMDs -> 1 wave/SIMD,
//    no 2-wave straggler SIMDs (K=8 would give 1032 waves).
//  - Register prefetch ring of PF=16 timesteps: issue next group's 16 loads,
//    compute current group's 16 steps (~600 cyc) -> load latency hidden.
//  - Per-step scalars via native v_rcp/v_rsq (1 ulp; threshold is 0.1).

#define NN 16
#define TT 2000
#define FCC 514               // F*C
#define SERIES (NN * FCC)     // 8224
#define BETAF 0.99f
#define OMBF 0.01f            // 1 - beta
#define EPSF 1e-5f
#define NCHUNK 7
#define CLEN 286              // ceil(2000/7)
#define WARM 512
#define PF 16

__global__ __launch_bounds__(64)
void ewma_kernel(const float* __restrict__ s, float* __restrict__ out) {
    const int tid = blockIdx.x * 64 + threadIdx.x;
    if (tid >= SERIES) return;

    const int chunk = blockIdx.y;
    const int t_out = chunk * CLEN;
    int t_end = t_out + CLEN; if (t_end > TT) t_end = TT;
    int t0 = t_out - WARM;     if (t0 < 0) t0 = 0;

    const int n  = tid / FCC;
    const int fc = tid - n * FCC;

    // beta^t0 via double binary exponentiation (once per thread, ~11 muls)
    double bd = 0.99, acc = 1.0;
    int e = t0;
    while (e) { if (e & 1) acc *= bd; bd *= bd; e >>= 1; }
    float bt = (float)acc;

    float v1 = 0.0f, v2p = 0.0f, S = 0.0f;

    const size_t base = (size_t)n * TT * FCC + (size_t)fc + (size_t)t0 * FCC;
    const float* p  = s   + base;
    float*       po = out + base;

    auto step = [&](float x) -> float {
        bt *= BETAF;
        const float om = 1.0f - bt;
        const float r  = __builtin_amdgcn_rcpf(om);   // 1/(1-beta^t)
        v1 = fmaf(BETAF, v1 - x, x);                  // beta*v1 + (1-beta)*x
        const float v2 = v1 * r;
        const float w  = OMBF * r;                    // (1-beta)/(1-beta^t)
        const float d  = x - v2;
        const float dp = x - v2p;
        const float pr = d * dp;
        S = fmaf(w, pr - S, S);                       // (1-w)*S + w*pr
        S = fmaxf(S, 0.0f);
        const float y = d * __builtin_amdgcn_rsqf(S + EPSF);
        v2p = v2;
        return y;
    };

    // initial fill (every chunk has >= 284 steps >= PF)
    float buf[PF];
    #pragma unroll
    for (int i = 0; i < PF; ++i) buf[i] = p[i * FCC];

    int t = t0;
    while (t + PF <= t_end) {
        // prefetch next group's 16 values (clamped in-bounds re-read when the
        // next group doesn't exist; values then unused since loop exits)
        const float* pf_ptr = (t + 2 * PF <= t_end) ? (p + PF * FCC) : p;
        float nbuf[PF];
        #pragma unroll
        for (int i = 0; i < PF; ++i) nbuf[i] = pf_ptr[i * FCC];

        #pragma unroll
        for (int i = 0; i < PF; ++i) {
            const float y = step(buf[i]);
            if (t >= t_out) {                 // loop-invariant: full-output group
                po[i * FCC] = y;
            } else if (t + i >= t_out) {      // mixed warmup/output boundary group
                po[i * FCC] = y;
            }
        }

        #pragma unroll
        for (int i = 0; i < PF; ++i) buf[i] = nbuf[i];
        p  += PF * FCC;
        po += PF * FCC;
        t  += PF;
    }
    // tail (< PF steps)
    for (; t < t_end; ++t) {
        const float y = step(*p);
        if (t >= t_out) *po = y;
        p  += FCC;
        po += FCC;
    }
}

extern "C" void kernel_launch(void* const* d_in, const int* in_sizes, int n_in,
                              void* d_out, int out_size, void* d_ws, size_t ws_size,
                              hipStream_t stream) {
    const float* s = (const float*)d_in[0];
    float* out = (float*)d_out;
    dim3 grid((SERIES + 63) / 64, NCHUNK);   // 129 x 7 blocks of 64
    ewma_kernel<<<grid, dim3(64), 0, stream>>>(s, out);
}